// Round 12
// baseline (255.798 us; speedup 1.0000x reference)
//
#include <hip/hip_runtime.h>

namespace {

using f4 = __attribute__((ext_vector_type(4))) float;
using s8 = __attribute__((ext_vector_type(8))) short;            // 8 bf16
using u16x8 = __attribute__((ext_vector_type(8))) unsigned short;

constexpr int kN = 4096;
constexpr int kC = 256;
constexpr int kD = 32;
constexpr int kB = 8;
constexpr int BR = 64;
constexpr int NT = 128;   // 32-key tiles
constexpr int NI = 64;    // 64-key iterations in attn

__device__ __forceinline__ unsigned short f2bf(float x) {
  union { float f; unsigned u; } v{x};
  unsigned r = v.u + 0x7fffu + ((v.u >> 16) & 1u);
  return (unsigned short)(r >> 16);
}
__device__ __forceinline__ float bf2f(unsigned short h) {
  union { unsigned u; float f; } v{((unsigned)h) << 16};
  return v.f;
}
// packed RTNE f32->bf16 pair: D[15:0]=bf16(a), D[31:16]=bf16(b).
// Bit-identical to f2bf for normal values; 1 instr replaces ~11.
__device__ __forceinline__ unsigned cvt_pk_bf16(float a, float b) {
  unsigned r;
  asm("v_cvt_pk_bf16_f32 %0, %1, %2" : "=v"(r) : "v"(a), "v"(b));
  return r;
}
// LDS-only barrier: orders pA traffic without draining VMEM queues
// (__syncthreads would emit s_waitcnt vmcnt(0) and kill cross-barrier
// prefetch). All VMEM here is per-thread register data — no cross-wave
// global ordering needed.
__device__ __forceinline__ void lds_barrier() {
  asm volatile("s_waitcnt lgkmcnt(0)\ns_barrier" ::: "memory");
}

// ---------------------------------------------------------------------------
// Weight pre-swizzle: wq/wk/wv -> hi/lo bf16 A-frag layout (unchanged).
// wswz[mt][plane][ks][slot=quad*16+m][j]; m-tiles: 0,1=q 2,3=k 4..19=v.
// ---------------------------------------------------------------------------
__global__ void wswz_kernel(const float* __restrict__ wq,
                            const float* __restrict__ wk,
                            const float* __restrict__ wv,
                            unsigned short* __restrict__ wswz) {
  const int mt = blockIdx.x;  // 0..19
  const int t = threadIdx.x;
  const int s = t & 63;
  const int m = s & 15, quad = s >> 4;
  const int kk = t >> 6;
  const float* w;
  int row0;
  if (mt < 2) { w = wq; row0 = mt * 16; }
  else if (mt < 4) { w = wk; row0 = (mt - 2) * 16; }
  else { w = wv; row0 = (mt - 4) * 16; }
  const float* wrow = w + (size_t)(row0 + m) * kC;
#pragma unroll
  for (int e = 0; e < 2; ++e) {
    const int ks = kk * 2 + e;
    const int c0 = ks * 32 + quad * 8;
    u16x8 hi, lo;
#pragma unroll
    for (int j = 0; j < 8; ++j) {
      const float f = wrow[c0 + j];
      const unsigned short h = f2bf(f);
      hi[j] = h;
      lo[j] = f2bf(f - bf2f(h));
    }
    const size_t base = (size_t)mt * 8192 + (size_t)ks * 512 + (size_t)s * 8;
    *(u16x8*)&wswz[base] = hi;
    *(u16x8*)&wswz[base + 4096] = lo;
  }
}

// ---------------------------------------------------------------------------
// QKV v2: barrier-free. Weight frags load directly global->VGPR (same
// addresses across waves/blocks -> L1-served). V epilogue transposes through
// a PER-WAVE 768B LDS tile synced by lgkmcnt only. 8 waves/CU flow freely.
// NOTE: launched TWICE this round as a timing probe (idempotent — second
// launch rewrites identical bytes); Δdur_us isolates qkv's true duration.
// ---------------------------------------------------------------------------
__global__ __launch_bounds__(256, 2) void qkv_kernel(
    const float* __restrict__ x, const float* __restrict__ bq,
    const float* __restrict__ bk, const float* __restrict__ bv,
    const unsigned short* __restrict__ wswz, float* __restrict__ q,
    unsigned short* __restrict__ kswz, unsigned short* __restrict__ vswz) {
  __shared__ __align__(16) unsigned short vls[4][16 * 24];  // per-wave tiles
  const int t = threadIdx.x, lane = t & 63, wvid = t >> 6;
  const int nn = lane & 15, quad = lane >> 4;
  const int b = blockIdx.y, nb = blockIdx.x * 64;
  const int n_g = nb + wvid * 16 + nn;

  // resident x B-frags (hi/lo bf16), 8 k-steps; pair-wise cvt_pk split
  s8 xh[8], xl[8];
#pragma unroll
  for (int ks = 0; ks < 8; ++ks) {
#pragma unroll
    for (int j = 0; j < 8; j += 2) {
      const int c = ks * 32 + quad * 8 + j;
      const float f0 = x[((size_t)(b * kC + c)) * kN + n_g];
      const float f1 = x[((size_t)(b * kC + c + 1)) * kN + n_g];
      const unsigned ph = cvt_pk_bf16(f0, f1);
      union { unsigned u; float f; } h0{ph << 16}, h1{ph & 0xffff0000u};
      const unsigned pl = cvt_pk_bf16(f0 - h0.f, f1 - h1.f);
      xh[ks][j] = (short)(ph & 0xffffu);
      xh[ks][j + 1] = (short)(ph >> 16);
      xl[ks][j] = (short)(pl & 0xffffu);
      xl[ks][j + 1] = (short)(pl >> 16);
    }
  }

  const s8* wf = (const s8*)wswz;  // m-tile stride 1024 s8; lo plane +512
  const f4 z = {0.f, 0.f, 0.f, 0.f};
  const int ml = quad * 4;

  // ---- Q (m-tiles 0,1): 3-product hi/lo ----
#pragma unroll
  for (int mt = 0; mt < 2; ++mt) {
    f4 acc = z;
#pragma unroll
    for (int ks = 0; ks < 8; ++ks) {
      const s8 ah = wf[mt * 1024 + ks * 64 + lane];
      const s8 al = wf[mt * 1024 + 512 + ks * 64 + lane];
      acc = __builtin_amdgcn_mfma_f32_16x16x32_bf16(ah, xh[ks], acc, 0, 0, 0);
      acc = __builtin_amdgcn_mfma_f32_16x16x32_bf16(ah, xl[ks], acc, 0, 0, 0);
      acc = __builtin_amdgcn_mfma_f32_16x16x32_bf16(al, xh[ks], acc, 0, 0, 0);
    }
#pragma unroll
    for (int r = 0; r < 4; ++r)
      q[((size_t)(b * kD + mt * 16 + ml + r)) * kN + n_g] =
          acc[r] + bq[mt * 16 + ml + r];
  }

  // ---- K (m-tiles 2,3): 3-product hi/lo, even/odd-split swizzled store ----
#pragma unroll
  for (int mk = 0; mk < 2; ++mk) {
    const int mt = 2 + mk;
    f4 acc = z;
#pragma unroll
    for (int ks = 0; ks < 8; ++ks) {
      const s8 ah = wf[mt * 1024 + ks * 64 + lane];
      const s8 al = wf[mt * 1024 + 512 + ks * 64 + lane];
      acc = __builtin_amdgcn_mfma_f32_16x16x32_bf16(ah, xh[ks], acc, 0, 0, 0);
      acc = __builtin_amdgcn_mfma_f32_16x16x32_bf16(ah, xl[ks], acc, 0, 0, 0);
      acc = __builtin_amdgcn_mfma_f32_16x16x32_bf16(al, xh[ks], acc, 0, 0, 0);
    }
    const int nt = n_g >> 5, key5 = n_g & 31;
    const int kb = key5 & 1, cpos = key5 >> 1;
    ushort4 hi, lo;
#pragma unroll
    for (int r = 0; r < 4; ++r) {
      const float val = acc[r] + bk[mk * 16 + ml + r];
      const unsigned short h = f2bf(val);
      ((unsigned short*)&hi)[r] = h;
      ((unsigned short*)&lo)[r] = f2bf(val - bf2f(h));
    }
    const int d0 = mk * 16 + ml;
    const int qk = d0 >> 3, j0 = d0 & 7;
    const size_t base = ((size_t)((b * NT + nt) * 4 + kb)) * 512 +
                        (size_t)(qk * 16 + cpos) * 8 + j0;
    *(ushort4*)&kswz[base] = hi;
    *(ushort4*)&kswz[base + 1024] = lo;
  }

  // ---- V (m-tiles 4..19): 2-product, per-wave LDS transpose epilogue ----
  unsigned short* vw = vls[wvid];
  for (int cb = 0; cb < 16; ++cb) {
    const int mt = 4 + cb;
    f4 acc = z;
#pragma unroll
    for (int ks = 0; ks < 8; ++ks) {
      const s8 ah = wf[mt * 1024 + ks * 64 + lane];
      acc = __builtin_amdgcn_mfma_f32_16x16x32_bf16(ah, xh[ks], acc, 0, 0, 0);
      acc = __builtin_amdgcn_mfma_f32_16x16x32_bf16(ah, xl[ks], acc, 0, 0, 0);
    }
#pragma unroll
    for (int r = 0; r < 4; ++r)
      vw[(ml + r) * 24 + nn] = f2bf(acc[r] + bv[cb * 16 + ml + r]);
    asm volatile("s_waitcnt lgkmcnt(0)" ::: "memory");  // wave-local sync
    if (lane < 32) {
      const int cv = lane & 15, o = lane >> 4;
      const u16x8 row = *(const u16x8*)&vw[cv * 24 + o * 8];  // 16B-aligned
      const int tok0 = wvid * 16 + o * 8;  // token offset within 64-block
      const int nt = blockIdx.x * 2 + (tok0 >> 5);
      const int quadv = (tok0 & 31) >> 3;
      *(u16x8*)&vswz[((size_t)(b * NT + nt)) * 8192 + (size_t)cb * 512 +
                     (size_t)(quadv * 16 + cv) * 8] = row;
    }
    // register dep on `row` orders the b128 read before next tile's writes
  }
}

// ---------------------------------------------------------------------------
// MFMA flash attention v5e (round-11 passing version, verbatim).
// ---------------------------------------------------------------------------
__global__ __launch_bounds__(256, 2) void attn_kernel(
    const float* __restrict__ q, const unsigned short* __restrict__ kswz,
    const unsigned short* __restrict__ vswz, const float* __restrict__ x,
    const float* __restrict__ gamma, float* __restrict__ out) {
  __shared__ __align__(16) char smem[18432];       // 2 x 9216 pA buffers
  __shared__ float lsh[64];                        // per-query l exchange
  unsigned* const pA0 = (unsigned*)smem;           // rows stride 36 uints
  unsigned* const pA1 = (unsigned*)(smem + 9216);

  const int t = threadIdx.x;
  const int lane = t & 63;
  const int wvid = t >> 6;
  const int c = lane & 15;
  const int quad = lane >> 4;
  const int b = blockIdx.y;
  const int nb = blockIdx.x * BR;

  // Q A-frags hi/lo
  s8 qfh, qfl;
  {
    const int nq = nb + wvid * 16 + c;
#pragma unroll
    for (int j = 0; j < 8; ++j) {
      const int d = quad * 8 + j;
      const float f = q[((size_t)(b * kD + d)) * kN + nq];
      const unsigned short h = f2bf(f);
      qfh[j] = (short)h;
      qfl[j] = (short)f2bf(f - bf2f(h));
    }
  }

  f4 O[4][4];
#pragma unroll
  for (int i = 0; i < 4; ++i)
#pragma unroll
    for (int jj = 0; jj < 4; ++jj) O[i][jj] = (f4){0.f, 0.f, 0.f, 0.f};
  float lsum[4] = {0.f, 0.f, 0.f, 0.f};  // partial l for own 4 queries

  const s8* gkb = (const s8*)(kswz + ((size_t)(b * NT)) * 2048);
  const s8* gvb = (const s8*)(vswz + ((size_t)(b * NT)) * 8192);

  s8 kfA[2][4], vfA[2][4], kfB[2][4], vfB[2][4];

  // preload iter 0 into A-buffers
#pragma unroll
  for (int h = 0; h < 2; ++h) {
    const s8* gk = gkb + (size_t)h * 256;
#pragma unroll
    for (int f = 0; f < 4; ++f) kfA[h][f] = gk[f * 64 + lane];
  }
#pragma unroll
  for (int h = 0; h < 2; ++h) {
    const s8* gv = gvb + (size_t)h * 1024;
#pragma unroll
    for (int f = 0; f < 4; ++f) vfA[h][f] = gv[(wvid * 4 + f) * 64 + lane];
  }

  // one 64-key iteration; prefetches it+1 into (kn, vn). Prefetch at it=63
  // reads in-bounds workspace garbage (never consumed).
  auto iter = [&](int it, s8 (&kc)[2][4], s8 (&vc)[2][4], s8 (&kn)[2][4],
                  s8 (&vn)[2][4], unsigned* pc) {
    // ---- S = Q.K (hi/lo, fp32-class) ----
    const f4 z = {0.f, 0.f, 0.f, 0.f};
    f4 se[2], so[2];
#pragma unroll
    for (int h = 0; h < 2; ++h) {
      f4 a = __builtin_amdgcn_mfma_f32_16x16x32_bf16(qfl, kc[h][0], z, 0, 0, 0);
      a = __builtin_amdgcn_mfma_f32_16x16x32_bf16(qfh, kc[h][2], a, 0, 0, 0);
      a = __builtin_amdgcn_mfma_f32_16x16x32_bf16(qfh, kc[h][0], a, 0, 0, 0);
      se[h] = a;
      f4 bb = __builtin_amdgcn_mfma_f32_16x16x32_bf16(qfl, kc[h][1], z, 0, 0, 0);
      bb = __builtin_amdgcn_mfma_f32_16x16x32_bf16(qfh, kc[h][3], bb, 0, 0, 0);
      bb = __builtin_amdgcn_mfma_f32_16x16x32_bf16(qfh, kc[h][1], bb, 0, 0, 0);
      so[h] = bb;
    }

    // ---- prefetch it+1 (K first; stays in flight across the barrier) ----
    {
      const s8* gk = gkb + (size_t)((it + 1) * 2) * 256;
#pragma unroll
      for (int h = 0; h < 2; ++h)
#pragma unroll
        for (int f = 0; f < 4; ++f) kn[h][f] = gk[h * 256 + f * 64 + lane];
      const s8* gv = gvb + (size_t)((it + 1) * 2) * 1024;
#pragma unroll
      for (int h = 0; h < 2; ++h)
#pragma unroll
        for (int f = 0; f < 4; ++f)
          vn[h][f] = gv[h * 1024 + (wvid * 4 + f) * 64 + lane];
    }

    // ---- p = exp(e) (no-max: |e| bounded, fp32 range safe) ----
    // pack via cvt_pk; l accumulated from the SAME bf16-rounded values
    // (extract from pk) so O/l numerics match the ones-MFMA path.
#pragma unroll
    for (int h = 0; h < 2; ++h)
#pragma unroll
      for (int r = 0; r < 4; ++r) {
        const float pe = __expf(se[h][r]);
        const float po = __expf(so[h][r]);
        const unsigned pk = cvt_pk_bf16(pe, po);
        union { unsigned u; float f; } fe{pk << 16}, fo{pk & 0xffff0000u};
        lsum[r] += fe.f + fo.f;
        pc[(wvid * 16 + quad * 4 + r) * 36 + h * 16 + c] = pk;
      }
    lds_barrier();  // pA visible; VMEM prefetches remain in flight

    // ---- PV ----
    const unsigned short* pcs = (const unsigned short*)pc;
    __builtin_amdgcn_s_setprio(1);
#pragma unroll
    for (int rb = 0; rb < 4; ++rb) {
      const s8 a0 = *(const s8*)&pcs[(rb * 16 + c) * 72 + quad * 8];
      const s8 a1 = *(const s8*)&pcs[(rb * 16 + c) * 72 + 32 + quad * 8];
      O[rb][0] = __builtin_amdgcn_mfma_f32_16x16x32_bf16(a0, vc[0][0], O[rb][0], 0, 0, 0);
      O[rb][1] = __builtin_amdgcn_mfma_f32_16x16x32_bf16(a0, vc[0][1], O[rb][1], 0, 0, 0);
      O[rb][2] = __builtin_amdgcn_mfma_f32_16x16x32_bf16(a0, vc[0][2], O[rb][2], 0, 0, 0);
      O[rb][3] = __builtin_amdgcn_mfma_f32_16x16x32_bf16(a0, vc[0][3], O[rb][3], 0, 0, 0);
      O[rb][0] = __builtin_amdgcn_mfma_f32_16x16x32_bf16(a1, vc[1][0], O[rb][0], 0, 0, 0);
      O[rb][1] = __builtin_amdgcn_mfma_f32_16x16x32_bf16(a1, vc[1][1], O[rb][1], 0, 0, 0);
      O[rb][2] = __builtin_amdgcn_mfma_f32_16x16x32_bf16(a1, vc[1][2], O[rb][2], 0, 0, 0);
      O[rb][3] = __builtin_amdgcn_mfma_f32_16x16x32_bf16(a1, vc[1][3], O[rb][3], 0, 0, 0);
    }
    __builtin_amdgcn_s_setprio(0);
    // no trailing barrier: next iter writes the other pA buffer; a wave can
    // lead by at most one barrier, and its next-parity writes are fenced by
    // the follower's lgkmcnt(0)+s_barrier.
  };

  for (int it2 = 0; it2 < NI / 2; ++it2) {
    iter(2 * it2, kfA, vfA, kfB, vfB, pA0);
    iter(2 * it2 + 1, kfB, vfB, kfA, vfA, pA1);
  }

  // ---- finalize l: reduce over the 16 c-lanes, exchange via lsh ----
#pragma unroll
  for (int s = 1; s < 16; s <<= 1)
#pragma unroll
    for (int r = 0; r < 4; ++r) lsum[r] += __shfl_xor(lsum[r], s, 64);
  if (c == 0) {
#pragma unroll
    for (int r = 0; r < 4; ++r) lsh[wvid * 16 + quad * 4 + r] = lsum[r];
  }
  lds_barrier();  // lsh visible to all waves

  // ---- epilogue: direct out = gamma*(O/l) + x, f4 per (rb,cb) ----
  const float gm = gamma[0];
#pragma unroll
  for (int rb = 0; rb < 4; ++rb) {
    float inv[4];
#pragma unroll
    for (int r = 0; r < 4; ++r) inv[r] = gm / lsh[rb * 16 + quad * 4 + r];
#pragma unroll
    for (int cb = 0; cb < 4; ++cb) {
      const int ch = wvid * 64 + cb * 16 + c;
      const size_t idx =
          ((size_t)(b * kC + ch)) * kN + nb + rb * 16 + quad * 4;
      const f4 x4 = *(const f4*)&x[idx];
      f4 o4;
#pragma unroll
      for (int r = 0; r < 4; ++r) o4[r] = O[rb][cb][r] * inv[r];
      *(f4*)&out[idx] = o4 + x4;
    }
  }
}

}  // namespace

extern "C" void kernel_launch(void* const* d_in, const int* in_sizes, int n_in,
                              void* d_out, int out_size, void* d_ws, size_t ws_size,
                              hipStream_t stream) {
  const float* x = (const float*)d_in[0];
  const float* wq = (const float*)d_in[1];
  const float* bq = (const float*)d_in[2];
  const float* wk = (const float*)d_in[3];
  const float* bk = (const float*)d_in[4];
  const float* wv = (const float*)d_in[5];
  const float* bv = (const float*)d_in[6];
  const float* gamma = (const float*)d_in[7];
  float* out = (float*)d_out;

  // ws: q fp32 4MB | kswz 4MB | vswz 16MB | wswz 640KB (also prefetch slack)
  float* qw = (float*)d_ws;
  unsigned short* kswz = (unsigned short*)(qw + (size_t)1048576);
  unsigned short* vswz = kswz + (size_t)2097152;
  unsigned short* wswz = vswz + (size_t)8388608;

  wswz_kernel<<<dim3(20), dim3(256), 0, stream>>>(wq, wk, wv, wswz);
  // TIMING PROBE: qkv launched twice (idempotent). Δdur_us vs round 11
  // = qkv's true duration; next round removes the extra launch.
  qkv_kernel<<<dim3(64, kB), dim3(256), 0, stream>>>(x, bq, bk, bv, wswz, qw,
                                                     kswz, vswz);
  qkv_kernel<<<dim3(64, kB), dim3(256), 0, stream>>>(x, bq, bk, bv, wswz, qw,
                                                     kswz, vswz);
  attn_kernel<<<dim3(kN / BR, kB), dim3(256), 0, stream>>>(qw, kswz, vswz, x,
                                                           gamma, out);
}

// Round 13
// 212.238 us; speedup vs baseline: 1.2052x; 1.2052x over previous
//
#include <hip/hip_runtime.h>

namespace {

using f4 = __attribute__((ext_vector_type(4))) float;
using s8 = __attribute__((ext_vector_type(8))) short;            // 8 bf16
using u16x8 = __attribute__((ext_vector_type(8))) unsigned short;

constexpr int kN = 4096;
constexpr int kC = 256;
constexpr int kD = 32;
constexpr int kB = 8;
constexpr int BR = 64;
constexpr int NT = 128;   // 32-key tiles
constexpr int NI = 64;    // 64-key iterations in attn

__device__ __forceinline__ unsigned short f2bf(float x) {
  union { float f; unsigned u; } v{x};
  unsigned r = v.u + 0x7fffu + ((v.u >> 16) & 1u);
  return (unsigned short)(r >> 16);
}
__device__ __forceinline__ float bf2f(unsigned short h) {
  union { unsigned u; float f; } v{((unsigned)h) << 16};
  return v.f;
}
// packed RTNE f32->bf16 pair: D[15:0]=bf16(a), D[31:16]=bf16(b).
// Bit-identical to f2bf for normal values; 1 instr replaces ~11.
__device__ __forceinline__ unsigned cvt_pk_bf16(float a, float b) {
  unsigned r;
  asm("v_cvt_pk_bf16_f32 %0, %1, %2" : "=v"(r) : "v"(a), "v"(b));
  return r;
}
// LDS-only barrier: orders pA traffic without draining VMEM queues
// (__syncthreads would emit s_waitcnt vmcnt(0) and kill cross-barrier
// prefetch). All VMEM here is per-thread register data — no cross-wave
// global ordering needed.
__device__ __forceinline__ void lds_barrier() {
  asm volatile("s_waitcnt lgkmcnt(0)\ns_barrier" ::: "memory");
}

// ---------------------------------------------------------------------------
// Weight pre-swizzle: wq/wk/wv -> hi/lo bf16 A-frag layout (unchanged).
// wswz[mt][plane][ks][slot=quad*16+m][j]; m-tiles: 0,1=q 2,3=k 4..19=v.
// ---------------------------------------------------------------------------
__global__ void wswz_kernel(const float* __restrict__ wq,
                            const float* __restrict__ wk,
                            const float* __restrict__ wv,
                            unsigned short* __restrict__ wswz) {
  const int mt = blockIdx.x;  // 0..19
  const int t = threadIdx.x;
  const int s = t & 63;
  const int m = s & 15, quad = s >> 4;
  const int kk = t >> 6;
  const float* w;
  int row0;
  if (mt < 2) { w = wq; row0 = mt * 16; }
  else if (mt < 4) { w = wk; row0 = (mt - 2) * 16; }
  else { w = wv; row0 = (mt - 4) * 16; }
  const float* wrow = w + (size_t)(row0 + m) * kC;
#pragma unroll
  for (int e = 0; e < 2; ++e) {
    const int ks = kk * 2 + e;
    const int c0 = ks * 32 + quad * 8;
    u16x8 hi, lo;
#pragma unroll
    for (int j = 0; j < 8; ++j) {
      const float f = wrow[c0 + j];
      const unsigned short h = f2bf(f);
      hi[j] = h;
      lo[j] = f2bf(f - bf2f(h));
    }
    const size_t base = (size_t)mt * 8192 + (size_t)ks * 512 + (size_t)s * 8;
    *(u16x8*)&wswz[base] = hi;
    *(u16x8*)&wswz[base + 4096] = lo;
  }
}

// ---------------------------------------------------------------------------
// QKV v3: occupancy fix. r12 probe measured qkv = 33us vs ~13us roofline;
// grid was 512 blocks = 2 blocks/CU = 8 waves/CU — latency-bound on L2
// weight loads + serialized V epilogue waits. Split the 20 m-tiles across
// blockIdx.z (z=0: Q+K+V0..5, z=1: V6..15) -> 1024 blocks, 4 blocks/CU
// (launch_bounds(256,4)), 16 waves/CU. All per-tile code and indexing is
// byte-identical to the passing r11 version; z only selects tile ranges.
// Cost: x frags loaded by both z-blocks (+16MB HBM) and VGPR capped at 128.
// ---------------------------------------------------------------------------
__global__ __launch_bounds__(256, 4) void qkv_kernel(
    const float* __restrict__ x, const float* __restrict__ bq,
    const float* __restrict__ bk, const float* __restrict__ bv,
    const unsigned short* __restrict__ wswz, float* __restrict__ q,
    unsigned short* __restrict__ kswz, unsigned short* __restrict__ vswz) {
  __shared__ __align__(16) unsigned short vls[4][16 * 24];  // per-wave tiles
  const int t = threadIdx.x, lane = t & 63, wvid = t >> 6;
  const int nn = lane & 15, quad = lane >> 4;
  const int b = blockIdx.y, nb = blockIdx.x * 64;
  const int z = blockIdx.z;            // 0: Q+K+V[0,6) ; 1: V[6,16)
  const int n_g = nb + wvid * 16 + nn;

  // resident x B-frags (hi/lo bf16), 8 k-steps; pair-wise cvt_pk split
  s8 xh[8], xl[8];
#pragma unroll
  for (int ks = 0; ks < 8; ++ks) {
#pragma unroll
    for (int j = 0; j < 8; j += 2) {
      const int c = ks * 32 + quad * 8 + j;
      const float f0 = x[((size_t)(b * kC + c)) * kN + n_g];
      const float f1 = x[((size_t)(b * kC + c + 1)) * kN + n_g];
      const unsigned ph = cvt_pk_bf16(f0, f1);
      union { unsigned u; float f; } h0{ph << 16}, h1{ph & 0xffff0000u};
      const unsigned pl = cvt_pk_bf16(f0 - h0.f, f1 - h1.f);
      xh[ks][j] = (short)(ph & 0xffffu);
      xh[ks][j + 1] = (short)(ph >> 16);
      xl[ks][j] = (short)(pl & 0xffffu);
      xl[ks][j + 1] = (short)(pl >> 16);
    }
  }

  const s8* wf = (const s8*)wswz;  // m-tile stride 1024 s8; lo plane +512
  const f4 z4 = {0.f, 0.f, 0.f, 0.f};
  const int ml = quad * 4;

  if (z == 0) {
    // ---- Q (m-tiles 0,1): 3-product hi/lo ----
#pragma unroll
    for (int mt = 0; mt < 2; ++mt) {
      f4 acc = z4;
#pragma unroll
      for (int ks = 0; ks < 8; ++ks) {
        const s8 ah = wf[mt * 1024 + ks * 64 + lane];
        const s8 al = wf[mt * 1024 + 512 + ks * 64 + lane];
        acc = __builtin_amdgcn_mfma_f32_16x16x32_bf16(ah, xh[ks], acc, 0, 0, 0);
        acc = __builtin_amdgcn_mfma_f32_16x16x32_bf16(ah, xl[ks], acc, 0, 0, 0);
        acc = __builtin_amdgcn_mfma_f32_16x16x32_bf16(al, xh[ks], acc, 0, 0, 0);
      }
#pragma unroll
      for (int r = 0; r < 4; ++r)
        q[((size_t)(b * kD + mt * 16 + ml + r)) * kN + n_g] =
            acc[r] + bq[mt * 16 + ml + r];
    }

    // ---- K (m-tiles 2,3): 3-product hi/lo, even/odd-split swz store ----
#pragma unroll
    for (int mk = 0; mk < 2; ++mk) {
      const int mt = 2 + mk;
      f4 acc = z4;
#pragma unroll
      for (int ks = 0; ks < 8; ++ks) {
        const s8 ah = wf[mt * 1024 + ks * 64 + lane];
        const s8 al = wf[mt * 1024 + 512 + ks * 64 + lane];
        acc = __builtin_amdgcn_mfma_f32_16x16x32_bf16(ah, xh[ks], acc, 0, 0, 0);
        acc = __builtin_amdgcn_mfma_f32_16x16x32_bf16(ah, xl[ks], acc, 0, 0, 0);
        acc = __builtin_amdgcn_mfma_f32_16x16x32_bf16(al, xh[ks], acc, 0, 0, 0);
      }
      const int nt = n_g >> 5, key5 = n_g & 31;
      const int kb = key5 & 1, cpos = key5 >> 1;
      ushort4 hi, lo;
#pragma unroll
      for (int r = 0; r < 4; ++r) {
        const float val = acc[r] + bk[mk * 16 + ml + r];
        const unsigned short h = f2bf(val);
        ((unsigned short*)&hi)[r] = h;
        ((unsigned short*)&lo)[r] = f2bf(val - bf2f(h));
      }
      const int d0 = mk * 16 + ml;
      const int qk = d0 >> 3, j0 = d0 & 7;
      const size_t base = ((size_t)((b * NT + nt) * 4 + kb)) * 512 +
                          (size_t)(qk * 16 + cpos) * 8 + j0;
      *(ushort4*)&kswz[base] = hi;
      *(ushort4*)&kswz[base + 1024] = lo;
    }
  }

  // ---- V tiles [cb0,cb1): 2-product, per-wave LDS transpose epilogue ----
  const int cb0 = z ? 6 : 0, cb1 = z ? 16 : 6;
  unsigned short* vw = vls[wvid];
  for (int cb = cb0; cb < cb1; ++cb) {
    const int mt = 4 + cb;
    f4 acc = z4;
#pragma unroll
    for (int ks = 0; ks < 8; ++ks) {
      const s8 ah = wf[mt * 1024 + ks * 64 + lane];
      acc = __builtin_amdgcn_mfma_f32_16x16x32_bf16(ah, xh[ks], acc, 0, 0, 0);
      acc = __builtin_amdgcn_mfma_f32_16x16x32_bf16(ah, xl[ks], acc, 0, 0, 0);
    }
#pragma unroll
    for (int r = 0; r < 4; ++r)
      vw[(ml + r) * 24 + nn] = f2bf(acc[r] + bv[cb * 16 + ml + r]);
    asm volatile("s_waitcnt lgkmcnt(0)" ::: "memory");  // wave-local sync
    if (lane < 32) {
      const int cv = lane & 15, o = lane >> 4;
      const u16x8 row = *(const u16x8*)&vw[cv * 24 + o * 8];  // 16B-aligned
      const int tok0 = wvid * 16 + o * 8;  // token offset within 64-block
      const int nt = blockIdx.x * 2 + (tok0 >> 5);
      const int quadv = (tok0 & 31) >> 3;
      *(u16x8*)&vswz[((size_t)(b * NT + nt)) * 8192 + (size_t)cb * 512 +
                     (size_t)(quadv * 16 + cv) * 8] = row;
    }
    // register dep on `row` orders the b128 read before next tile's writes
  }
}

// ---------------------------------------------------------------------------
// MFMA flash attention v5e (round-11 passing version, verbatim).
// ---------------------------------------------------------------------------
__global__ __launch_bounds__(256, 2) void attn_kernel(
    const float* __restrict__ q, const unsigned short* __restrict__ kswz,
    const unsigned short* __restrict__ vswz, const float* __restrict__ x,
    const float* __restrict__ gamma, float* __restrict__ out) {
  __shared__ __align__(16) char smem[18432];       // 2 x 9216 pA buffers
  __shared__ float lsh[64];                        // per-query l exchange
  unsigned* const pA0 = (unsigned*)smem;           // rows stride 36 uints
  unsigned* const pA1 = (unsigned*)(smem + 9216);

  const int t = threadIdx.x;
  const int lane = t & 63;
  const int wvid = t >> 6;
  const int c = lane & 15;
  const int quad = lane >> 4;
  const int b = blockIdx.y;
  const int nb = blockIdx.x * BR;

  // Q A-frags hi/lo
  s8 qfh, qfl;
  {
    const int nq = nb + wvid * 16 + c;
#pragma unroll
    for (int j = 0; j < 8; ++j) {
      const int d = quad * 8 + j;
      const float f = q[((size_t)(b * kD + d)) * kN + nq];
      const unsigned short h = f2bf(f);
      qfh[j] = (short)h;
      qfl[j] = (short)f2bf(f - bf2f(h));
    }
  }

  f4 O[4][4];
#pragma unroll
  for (int i = 0; i < 4; ++i)
#pragma unroll
    for (int jj = 0; jj < 4; ++jj) O[i][jj] = (f4){0.f, 0.f, 0.f, 0.f};
  float lsum[4] = {0.f, 0.f, 0.f, 0.f};  // partial l for own 4 queries

  const s8* gkb = (const s8*)(kswz + ((size_t)(b * NT)) * 2048);
  const s8* gvb = (const s8*)(vswz + ((size_t)(b * NT)) * 8192);

  s8 kfA[2][4], vfA[2][4], kfB[2][4], vfB[2][4];

  // preload iter 0 into A-buffers
#pragma unroll
  for (int h = 0; h < 2; ++h) {
    const s8* gk = gkb + (size_t)h * 256;
#pragma unroll
    for (int f = 0; f < 4; ++f) kfA[h][f] = gk[f * 64 + lane];
  }
#pragma unroll
  for (int h = 0; h < 2; ++h) {
    const s8* gv = gvb + (size_t)h * 1024;
#pragma unroll
    for (int f = 0; f < 4; ++f) vfA[h][f] = gv[(wvid * 4 + f) * 64 + lane];
  }

  // one 64-key iteration; prefetches it+1 into (kn, vn). Prefetch at it=63
  // reads in-bounds workspace garbage (never consumed).
  auto iter = [&](int it, s8 (&kc)[2][4], s8 (&vc)[2][4], s8 (&kn)[2][4],
                  s8 (&vn)[2][4], unsigned* pc) {
    // ---- S = Q.K (hi/lo, fp32-class) ----
    const f4 z = {0.f, 0.f, 0.f, 0.f};
    f4 se[2], so[2];
#pragma unroll
    for (int h = 0; h < 2; ++h) {
      f4 a = __builtin_amdgcn_mfma_f32_16x16x32_bf16(qfl, kc[h][0], z, 0, 0, 0);
      a = __builtin_amdgcn_mfma_f32_16x16x32_bf16(qfh, kc[h][2], a, 0, 0, 0);
      a = __builtin_amdgcn_mfma_f32_16x16x32_bf16(qfh, kc[h][0], a, 0, 0, 0);
      se[h] = a;
      f4 bb = __builtin_amdgcn_mfma_f32_16x16x32_bf16(qfl, kc[h][1], z, 0, 0, 0);
      bb = __builtin_amdgcn_mfma_f32_16x16x32_bf16(qfh, kc[h][3], bb, 0, 0, 0);
      bb = __builtin_amdgcn_mfma_f32_16x16x32_bf16(qfh, kc[h][1], bb, 0, 0, 0);
      so[h] = bb;
    }

    // ---- prefetch it+1 (K first; stays in flight across the barrier) ----
    {
      const s8* gk = gkb + (size_t)((it + 1) * 2) * 256;
#pragma unroll
      for (int h = 0; h < 2; ++h)
#pragma unroll
        for (int f = 0; f < 4; ++f) kn[h][f] = gk[h * 256 + f * 64 + lane];
      const s8* gv = gvb + (size_t)((it + 1) * 2) * 1024;
#pragma unroll
      for (int h = 0; h < 2; ++h)
#pragma unroll
        for (int f = 0; f < 4; ++f)
          vn[h][f] = gv[h * 1024 + (wvid * 4 + f) * 64 + lane];
    }

    // ---- p = exp(e) (no-max: |e| bounded, fp32 range safe) ----
    // pack via cvt_pk; l accumulated from the SAME bf16-rounded values
    // (extract from pk) so O/l numerics match the ones-MFMA path.
#pragma unroll
    for (int h = 0; h < 2; ++h)
#pragma unroll
      for (int r = 0; r < 4; ++r) {
        const float pe = __expf(se[h][r]);
        const float po = __expf(so[h][r]);
        const unsigned pk = cvt_pk_bf16(pe, po);
        union { unsigned u; float f; } fe{pk << 16}, fo{pk & 0xffff0000u};
        lsum[r] += fe.f + fo.f;
        pc[(wvid * 16 + quad * 4 + r) * 36 + h * 16 + c] = pk;
      }
    lds_barrier();  // pA visible; VMEM prefetches remain in flight

    // ---- PV ----
    const unsigned short* pcs = (const unsigned short*)pc;
    __builtin_amdgcn_s_setprio(1);
#pragma unroll
    for (int rb = 0; rb < 4; ++rb) {
      const s8 a0 = *(const s8*)&pcs[(rb * 16 + c) * 72 + quad * 8];
      const s8 a1 = *(const s8*)&pcs[(rb * 16 + c) * 72 + 32 + quad * 8];
      O[rb][0] = __builtin_amdgcn_mfma_f32_16x16x32_bf16(a0, vc[0][0], O[rb][0], 0, 0, 0);
      O[rb][1] = __builtin_amdgcn_mfma_f32_16x16x32_bf16(a0, vc[0][1], O[rb][1], 0, 0, 0);
      O[rb][2] = __builtin_amdgcn_mfma_f32_16x16x32_bf16(a0, vc[0][2], O[rb][2], 0, 0, 0);
      O[rb][3] = __builtin_amdgcn_mfma_f32_16x16x32_bf16(a0, vc[0][3], O[rb][3], 0, 0, 0);
      O[rb][0] = __builtin_amdgcn_mfma_f32_16x16x32_bf16(a1, vc[1][0], O[rb][0], 0, 0, 0);
      O[rb][1] = __builtin_amdgcn_mfma_f32_16x16x32_bf16(a1, vc[1][1], O[rb][1], 0, 0, 0);
      O[rb][2] = __builtin_amdgcn_mfma_f32_16x16x32_bf16(a1, vc[1][2], O[rb][2], 0, 0, 0);
      O[rb][3] = __builtin_amdgcn_mfma_f32_16x16x32_bf16(a1, vc[1][3], O[rb][3], 0, 0, 0);
    }
    __builtin_amdgcn_s_setprio(0);
    // no trailing barrier: next iter writes the other pA buffer; a wave can
    // lead by at most one barrier, and its next-parity writes are fenced by
    // the follower's lgkmcnt(0)+s_barrier.
  };

  for (int it2 = 0; it2 < NI / 2; ++it2) {
    iter(2 * it2, kfA, vfA, kfB, vfB, pA0);
    iter(2 * it2 + 1, kfB, vfB, kfA, vfA, pA1);
  }

  // ---- finalize l: reduce over the 16 c-lanes, exchange via lsh ----
#pragma unroll
  for (int s = 1; s < 16; s <<= 1)
#pragma unroll
    for (int r = 0; r < 4; ++r) lsum[r] += __shfl_xor(lsum[r], s, 64);
  if (c == 0) {
#pragma unroll
    for (int r = 0; r < 4; ++r) lsh[wvid * 16 + quad * 4 + r] = lsum[r];
  }
  lds_barrier();  // lsh visible to all waves

  // ---- epilogue: direct out = gamma*(O/l) + x, f4 per (rb,cb) ----
  const float gm = gamma[0];
#pragma unroll
  for (int rb = 0; rb < 4; ++rb) {
    float inv[4];
#pragma unroll
    for (int r = 0; r < 4; ++r) inv[r] = gm / lsh[rb * 16 + quad * 4 + r];
#pragma unroll
    for (int cb = 0; cb < 4; ++cb) {
      const int ch = wvid * 64 + cb * 16 + c;
      const size_t idx =
          ((size_t)(b * kC + ch)) * kN + nb + rb * 16 + quad * 4;
      const f4 x4 = *(const f4*)&x[idx];
      f4 o4;
#pragma unroll
      for (int r = 0; r < 4; ++r) o4[r] = O[rb][cb][r] * inv[r];
      *(f4*)&out[idx] = o4 + x4;
    }
  }
}

}  // namespace

extern "C" void kernel_launch(void* const* d_in, const int* in_sizes, int n_in,
                              void* d_out, int out_size, void* d_ws, size_t ws_size,
                              hipStream_t stream) {
  const float* x = (const float*)d_in[0];
  const float* wq = (const float*)d_in[1];
  const float* bq = (const float*)d_in[2];
  const float* wk = (const float*)d_in[3];
  const float* bk = (const float*)d_in[4];
  const float* wv = (const float*)d_in[5];
  const float* bv = (const float*)d_in[6];
  const float* gamma = (const float*)d_in[7];
  float* out = (float*)d_out;

  // ws: q fp32 4MB | kswz 4MB | vswz 16MB | wswz 640KB (also prefetch slack)
  float* qw = (float*)d_ws;
  unsigned short* kswz = (unsigned short*)(qw + (size_t)1048576);
  unsigned short* vswz = kswz + (size_t)2097152;
  unsigned short* wswz = vswz + (size_t)8388608;

  wswz_kernel<<<dim3(20), dim3(256), 0, stream>>>(wq, wk, wv, wswz);
  // z-split: 1024 blocks -> 4 blocks/CU, 16 waves/CU (qkv was grid-capped
  // at 8 waves/CU and latency-bound; r12 probe measured 33us vs 13 roofline)
  qkv_kernel<<<dim3(64, kB, 2), dim3(256), 0, stream>>>(x, bq, bk, bv, wswz,
                                                        qw, kswz, vswz);
  attn_kernel<<<dim3(kN / BR, kB), dim3(256), 0, stream>>>(qw, kswz, vswz, x,
                                                           gamma, out);
}